// Round 3
// baseline (72396.057 us; speedup 1.0000x reference)
//
#include <hip/hip_runtime.h>
#include <hip/hip_cooperative_groups.h>

namespace cg = cooperative_groups;

#define T_DIM 512
#define B_DIM 256
#define S_DIMS 64
#define A_DIMS 16
#define E_DIM 128
#define H_DIM 512
#define X_DIM 384   // 3*E
#define G_DIM 1536  // 3*H

__device__ __forceinline__ float gelu_tanh(float x) {
    const float c = 0.7978845608028654f; // sqrt(2/pi)
    float x3 = x * x * x;
    return 0.5f * x * (1.0f + tanhf(c * (x + 0.044715f * x3)));
}

__device__ __forceinline__ float sigmoidf(float x) {
    return 1.0f / (1.0f + expf(-x));
}

// ---------------- Embedding kernel: x = [gelu(s@Ws+bs), gelu(a@Wa+ba), gelu(r@Wr+br)]
__global__ __launch_bounds__(256) void embed_kernel(
    const float* __restrict__ s, const float* __restrict__ a, const float* __restrict__ r,
    const float* __restrict__ Ws, const float* __restrict__ bs,
    const float* __restrict__ Wa, const float* __restrict__ ba,
    const float* __restrict__ Wr, const float* __restrict__ br,
    float* __restrict__ x)
{
    __shared__ float Ws_s[64][128];
    __shared__ float Wa_s[16][128];
    __shared__ float Wr_s[128], bs_s[128], ba_s[128], br_s[128];
    __shared__ float s_s[64][64];
    __shared__ float a_s[64][16];
    __shared__ float r_s[64];
    int tid = threadIdx.x;
    for (int i = tid; i < 64 * 128; i += 256) Ws_s[i >> 7][i & 127] = Ws[i];
    for (int i = tid; i < 16 * 128; i += 256) Wa_s[i >> 7][i & 127] = Wa[i];
    if (tid < 128) { Wr_s[tid] = Wr[tid]; bs_s[tid] = bs[tid]; ba_s[tid] = ba[tid]; br_s[tid] = br[tid]; }
    size_t row0 = (size_t)blockIdx.x * 64;
    for (int i = tid; i < 64 * 64; i += 256) s_s[i >> 6][i & 63] = s[row0 * 64 + i];
    for (int i = tid; i < 64 * 16; i += 256) a_s[i >> 4][i & 15] = a[row0 * 16 + i];
    if (tid < 64) r_s[tid] = r[row0 + tid];
    __syncthreads();
    int e = tid & 127, ty = tid >> 7;
    for (int rw = ty; rw < 64; rw += 2) {
        float accS = bs_s[e];
        #pragma unroll
        for (int k = 0; k < 64; ++k) accS += s_s[rw][k] * Ws_s[k][e];
        float accA = ba_s[e];
        #pragma unroll
        for (int k = 0; k < 16; ++k) accA += a_s[rw][k] * Wa_s[k][e];
        float accR = br_s[e] + r_s[rw] * Wr_s[e];
        size_t base = (row0 + rw) * X_DIM;
        x[base + e]       = gelu_tanh(accS);
        x[base + 128 + e] = gelu_tanh(accA);
        x[base + 256 + e] = gelu_tanh(accR);
    }
}

// ---------------- Gates GEMM: C[m][n] = sum_k A[m][k]*B[k][n] + bias[n]
__global__ __launch_bounds__(256) void gates_gemm(
    const float* __restrict__ A, const float* __restrict__ B,
    const float* __restrict__ bias, float* __restrict__ C)
{
    __shared__ float As[32][132];
    __shared__ float Bs[32][132];
    const int K = X_DIM;
    int tid = threadIdx.x;
    size_t m0 = (size_t)blockIdx.x * 128;
    int n0 = blockIdx.y * 128;
    int tx = tid & 15, ty = tid >> 4;
    float acc[8][8] = {};
    for (int k0 = 0; k0 < K; k0 += 32) {
        #pragma unroll
        for (int p = 0; p < 4; ++p) {
            int row = (tid >> 3) + p * 32;
            int k4 = (tid & 7) * 4;
            float4 v = *reinterpret_cast<const float4*>(&A[(m0 + row) * K + k0 + k4]);
            As[k4 + 0][row] = v.x; As[k4 + 1][row] = v.y;
            As[k4 + 2][row] = v.z; As[k4 + 3][row] = v.w;
        }
        {
            int k = tid >> 3;
            int cb = (tid & 7) * 16;
            #pragma unroll
            for (int q = 0; q < 4; ++q) {
                float4 v = *reinterpret_cast<const float4*>(&B[(size_t)(k0 + k) * G_DIM + n0 + cb + q * 4]);
                *reinterpret_cast<float4*>(&Bs[k][cb + q * 4]) = v;
            }
        }
        __syncthreads();
        #pragma unroll
        for (int k = 0; k < 32; ++k) {
            float4 a0 = *reinterpret_cast<const float4*>(&As[k][ty * 8]);
            float4 a1 = *reinterpret_cast<const float4*>(&As[k][ty * 8 + 4]);
            float4 b0 = *reinterpret_cast<const float4*>(&Bs[k][tx * 8]);
            float4 b1 = *reinterpret_cast<const float4*>(&Bs[k][tx * 8 + 4]);
            float av[8] = {a0.x, a0.y, a0.z, a0.w, a1.x, a1.y, a1.z, a1.w};
            float bv[8] = {b0.x, b0.y, b0.z, b0.w, b1.x, b1.y, b1.z, b1.w};
            #pragma unroll
            for (int i = 0; i < 8; ++i)
                #pragma unroll
                for (int j = 0; j < 8; ++j)
                    acc[i][j] += av[i] * bv[j];
        }
        __syncthreads();
    }
    #pragma unroll
    for (int i = 0; i < 8; ++i) {
        size_t crow = (m0 + ty * 8 + i) * G_DIM + n0 + tx * 8;
        float4 o0, o1;
        o0.x = acc[i][0] + bias[n0 + tx * 8 + 0];
        o0.y = acc[i][1] + bias[n0 + tx * 8 + 1];
        o0.z = acc[i][2] + bias[n0 + tx * 8 + 2];
        o0.w = acc[i][3] + bias[n0 + tx * 8 + 3];
        o1.x = acc[i][4] + bias[n0 + tx * 8 + 4];
        o1.y = acc[i][5] + bias[n0 + tx * 8 + 5];
        o1.z = acc[i][6] + bias[n0 + tx * 8 + 6];
        o1.w = acc[i][7] + bias[n0 + tx * 8 + 7];
        *reinterpret_cast<float4*>(&C[crow]) = o0;
        *reinterpret_cast<float4*>(&C[crow + 4]) = o1;
    }
}

// ---------------- Persistent cooperative GRU: nt steps, 2 grid syncs/step.
// 256 blocks x 256 threads. Block bid: rg = bid>>5 (8 row groups of 32 rows),
// cg_ = bid&31. Phase A: zr cols nA = cg_*32 (32 cols of 1024). Phase B: a
// cols nB = cg_*16 (16 cols of 512). Weight slices LDS-stationary across steps.
__global__ __launch_bounds__(256) void gru_persistent(
    const float* __restrict__ gx,    // nt x B x G
    int nt,
    const float* __restrict__ hinit, // B x H or nullptr (t0 == 0)
    const float* __restrict__ w_h,   // 512 x 1536
    float* __restrict__ out_base,    // nt x B x H (out + t0*B*H)
    float* __restrict__ zbuf,        // B x H
    float* __restrict__ rhbuf)       // B x H
{
    cg::grid_group grid = cg::this_grid();
    const int tid = threadIdx.x;
    const int bid = blockIdx.x;
    const int rg = bid >> 5;
    const int cgi = bid & 31;
    const int m0 = rg * 32;
    const int nA = cgi * 32;
    const int nB = cgi * 16;

    // LDS: wA 64KB + wB 32KB + h tile ~8.7KB = ~105 KB -> 1 block/CU
    __shared__ float wA_s[32 * 512];
    __shared__ float wB_s[16 * 512];
    __shared__ float h_s[32][68];

    // ---- load stationary weight slices (once per launch), XOR-swizzled on
    // 16B granules so inner-loop b128 column reads are <=2-way bank aliased.
    for (int i = tid; i < 512 * 32; i += 256) {
        int k = i >> 5, c = i & 31;
        int kb = k >> 2, kl = k & 3;
        wA_s[c * 512 + (((kb ^ ((c >> 1) & 7)) << 2) | kl)] = w_h[(size_t)k * G_DIM + nA + c];
    }
    for (int i = tid; i < 512 * 16; i += 256) {
        int k = i >> 4, c = i & 15;
        int kb = k >> 2, kl = k & 3;
        wB_s[c * 512 + (((kb ^ (c & 7)) << 2) | kl)] = w_h[(size_t)k * G_DIM + 1024 + nB + c];
    }
    __syncthreads();

    const int tx = tid & 15;
    const int r0 = (tid >> 4) * 2;   // 2 rows per thread
    const int c0A = tx * 2;          // 2 cols per thread (phase A)
    const int sxA = tx & 7;          // swizzle key for phase A col pair
    const int sxB = tx & 7;          // phase B col = tx

    for (int s = 0; s < nt; ++s) {
        const float* hp = (s == 0) ? hinit : out_base + (size_t)(s - 1) * B_DIM * H_DIM;
        const float* gxs = gx + (size_t)s * B_DIM * G_DIM;
        float* out_t = out_base + (size_t)s * B_DIM * H_DIM;

        // ================= Phase A: zr = sigmoid(gx_zr + h @ Wzr)
        float a00 = 0.f, a01 = 0.f, a10 = 0.f, a11 = 0.f;
        if (hp) {
            for (int k0 = 0; k0 < H_DIM; k0 += 64) {
                #pragma unroll
                for (int p = 0; p < 2; ++p) {
                    int i = tid + p * 256;      // 512 float4 total
                    int rr = i >> 4;
                    int c4 = (i & 15) * 4;
                    float4 v = *reinterpret_cast<const float4*>(&hp[(size_t)(m0 + rr) * H_DIM + k0 + c4]);
                    *reinterpret_cast<float4*>(&h_s[rr][c4]) = v;
                }
                __syncthreads();
                #pragma unroll
                for (int k = 0; k < 64; k += 4) {
                    int kb = (k0 + k) >> 2;
                    float4 hv0 = *reinterpret_cast<const float4*>(&h_s[r0][k]);
                    float4 hv1 = *reinterpret_cast<const float4*>(&h_s[r0 + 1][k]);
                    float4 w0 = *reinterpret_cast<const float4*>(&wA_s[c0A * 512 + ((kb ^ sxA) << 2)]);
                    float4 w1 = *reinterpret_cast<const float4*>(&wA_s[(c0A + 1) * 512 + ((kb ^ sxA) << 2)]);
                    a00 = fmaf(hv0.x, w0.x, a00); a00 = fmaf(hv0.y, w0.y, a00);
                    a00 = fmaf(hv0.z, w0.z, a00); a00 = fmaf(hv0.w, w0.w, a00);
                    a01 = fmaf(hv0.x, w1.x, a01); a01 = fmaf(hv0.y, w1.y, a01);
                    a01 = fmaf(hv0.z, w1.z, a01); a01 = fmaf(hv0.w, w1.w, a01);
                    a10 = fmaf(hv1.x, w0.x, a10); a10 = fmaf(hv1.y, w0.y, a10);
                    a10 = fmaf(hv1.z, w0.z, a10); a10 = fmaf(hv1.w, w0.w, a10);
                    a11 = fmaf(hv1.x, w1.x, a11); a11 = fmaf(hv1.y, w1.y, a11);
                    a11 = fmaf(hv1.z, w1.z, a11); a11 = fmaf(hv1.w, w1.w, a11);
                }
                __syncthreads();
            }
        }
        // epilogue A: uniform branch per block (nA<512 -> z cols, else r cols)
        {
            float accs[2][2] = {{a00, a01}, {a10, a11}};
            #pragma unroll
            for (int i = 0; i < 2; ++i) {
                int row = m0 + r0 + i;
                #pragma unroll
                for (int j = 0; j < 2; ++j) {
                    int colG = nA + c0A + j;
                    float val = sigmoidf(gxs[(size_t)row * G_DIM + colG] + accs[i][j]);
                    if (nA < 512) {
                        zbuf[(size_t)row * H_DIM + colG] = val;
                    } else {
                        int c = colG - 512;
                        float hpv = hp ? hp[(size_t)row * H_DIM + c] : 0.0f;
                        rhbuf[(size_t)row * H_DIM + c] = val * hpv;
                    }
                }
            }
        }
        __threadfence();
        grid.sync();

        // ================= Phase B: a = tanh(gx_a + rh @ Wa); h = hp + z*(a-hp)
        float b0 = 0.f, b1 = 0.f;
        for (int k0 = 0; k0 < H_DIM; k0 += 64) {
            #pragma unroll
            for (int p = 0; p < 2; ++p) {
                int i = tid + p * 256;
                int rr = i >> 4;
                int c4 = (i & 15) * 4;
                float4 v = *reinterpret_cast<const float4*>(&rhbuf[(size_t)(m0 + rr) * H_DIM + k0 + c4]);
                *reinterpret_cast<float4*>(&h_s[rr][c4]) = v;
            }
            __syncthreads();
            #pragma unroll
            for (int k = 0; k < 64; k += 4) {
                int kb = (k0 + k) >> 2;
                float4 hv0 = *reinterpret_cast<const float4*>(&h_s[r0][k]);
                float4 hv1 = *reinterpret_cast<const float4*>(&h_s[r0 + 1][k]);
                float4 wv = *reinterpret_cast<const float4*>(&wB_s[tx * 512 + ((kb ^ sxB) << 2)]);
                b0 = fmaf(hv0.x, wv.x, b0); b0 = fmaf(hv0.y, wv.y, b0);
                b0 = fmaf(hv0.z, wv.z, b0); b0 = fmaf(hv0.w, wv.w, b0);
                b1 = fmaf(hv1.x, wv.x, b1); b1 = fmaf(hv1.y, wv.y, b1);
                b1 = fmaf(hv1.z, wv.z, b1); b1 = fmaf(hv1.w, wv.w, b1);
            }
            __syncthreads();
        }
        {
            int col = nB + tx;
            float accs[2] = {b0, b1};
            #pragma unroll
            for (int i = 0; i < 2; ++i) {
                int row = m0 + r0 + i;
                float av = tanhf(gxs[(size_t)row * G_DIM + 1024 + col] + accs[i]);
                float hpv = hp ? hp[(size_t)row * H_DIM + col] : 0.0f;
                float z = zbuf[(size_t)row * H_DIM + col];
                out_t[(size_t)row * H_DIM + col] = hpv + z * (av - hpv);
            }
        }
        __threadfence();
        grid.sync();
    }
}

extern "C" void kernel_launch(void* const* d_in, const int* in_sizes, int n_in,
                              void* d_out, int out_size, void* d_ws, size_t ws_size,
                              hipStream_t stream) {
    const float* states  = (const float*)d_in[0];
    const float* actions = (const float*)d_in[1];
    const float* rewards = (const float*)d_in[2];
    const float* Ws   = (const float*)d_in[3];
    const float* bs   = (const float*)d_in[4];
    const float* Wa   = (const float*)d_in[5];
    const float* ba   = (const float*)d_in[6];
    const float* Wr   = (const float*)d_in[7];
    const float* br   = (const float*)d_in[8];
    const float* w_i  = (const float*)d_in[9];
    const float* w_h  = (const float*)d_in[10];
    const float* bgru = (const float*)d_in[11];
    float* out = (float*)d_out;

    // ws layout: [zbuf: B*512][rhbuf: B*512][gx: chunk*B*1536][xbuf: chunk*B*384]
    size_t fixed = (size_t)2 * B_DIM * H_DIM * sizeof(float);
    size_t per_step = (size_t)B_DIM * (G_DIM + X_DIM) * sizeof(float);
    int chunk = (int)((ws_size > fixed ? ws_size - fixed : 0) / per_step);
    if (chunk > T_DIM) chunk = T_DIM;
    if (chunk < 1) chunk = 1;
    float* zbuf  = (float*)d_ws;
    float* rhbuf = zbuf + (size_t)B_DIM * H_DIM;
    float* gx    = rhbuf + (size_t)B_DIM * H_DIM;
    float* xbuf  = gx + (size_t)chunk * B_DIM * G_DIM;

    for (int t0 = 0; t0 < T_DIM; t0 += chunk) {
        int nt = (T_DIM - t0 < chunk) ? (T_DIM - t0) : chunk;
        int rows = nt * B_DIM;
        embed_kernel<<<rows / 64, 256, 0, stream>>>(
            states + (size_t)t0 * B_DIM * S_DIMS,
            actions + (size_t)t0 * B_DIM * A_DIMS,
            rewards + (size_t)t0 * B_DIM,
            Ws, bs, Wa, ba, Wr, br, xbuf);
        dim3 ggrid(rows / 128, G_DIM / 128);
        gates_gemm<<<ggrid, 256, 0, stream>>>(xbuf, w_i, bgru, gx);

        const float* hinit = (t0 == 0) ? nullptr : out + (size_t)(t0 - 1) * B_DIM * H_DIM;
        float* out_base = out + (size_t)t0 * B_DIM * H_DIM;
        const float* gx_c = gx;
        const float* wh_c = w_h;
        void* kargs[] = {(void*)&gx_c, (void*)&nt, (void*)&hinit, (void*)&wh_c,
                         (void*)&out_base, (void*)&zbuf, (void*)&rhbuf};
        hipLaunchCooperativeKernel((void*)gru_persistent, dim3(256), dim3(256),
                                   kargs, 0, stream);
    }
}

// Round 4
// 21262.828 us; speedup vs baseline: 3.4048x; 3.4048x over previous
//
#include <hip/hip_runtime.h>

#define T_DIM 512
#define B_DIM 256
#define S_DIMS 64
#define A_DIMS 16
#define E_DIM 128
#define H_DIM 512
#define X_DIM 384   // 3*E
#define G_DIM 1536  // 3*H

__device__ __forceinline__ float gelu_tanh(float x) {
    const float c = 0.7978845608028654f; // sqrt(2/pi)
    float x3 = x * x * x;
    return 0.5f * x * (1.0f + tanhf(c * (x + 0.044715f * x3)));
}

__device__ __forceinline__ float sigmoidf(float x) {
    return 1.0f / (1.0f + expf(-x));
}

// ---------------- Embedding kernel: x = [gelu(s@Ws+bs), gelu(a@Wa+ba), gelu(r@Wr+br)]
__global__ __launch_bounds__(256) void embed_kernel(
    const float* __restrict__ s, const float* __restrict__ a, const float* __restrict__ r,
    const float* __restrict__ Ws, const float* __restrict__ bs,
    const float* __restrict__ Wa, const float* __restrict__ ba,
    const float* __restrict__ Wr, const float* __restrict__ br,
    float* __restrict__ x)
{
    __shared__ float Ws_s[64][128];
    __shared__ float Wa_s[16][128];
    __shared__ float Wr_s[128], bs_s[128], ba_s[128], br_s[128];
    __shared__ float s_s[64][64];
    __shared__ float a_s[64][16];
    __shared__ float r_s[64];
    int tid = threadIdx.x;
    for (int i = tid; i < 64 * 128; i += 256) Ws_s[i >> 7][i & 127] = Ws[i];
    for (int i = tid; i < 16 * 128; i += 256) Wa_s[i >> 7][i & 127] = Wa[i];
    if (tid < 128) { Wr_s[tid] = Wr[tid]; bs_s[tid] = bs[tid]; ba_s[tid] = ba[tid]; br_s[tid] = br[tid]; }
    size_t row0 = (size_t)blockIdx.x * 64;
    for (int i = tid; i < 64 * 64; i += 256) s_s[i >> 6][i & 63] = s[row0 * 64 + i];
    for (int i = tid; i < 64 * 16; i += 256) a_s[i >> 4][i & 15] = a[row0 * 16 + i];
    if (tid < 64) r_s[tid] = r[row0 + tid];
    __syncthreads();
    int e = tid & 127, ty = tid >> 7;
    for (int rw = ty; rw < 64; rw += 2) {
        float accS = bs_s[e];
        #pragma unroll
        for (int k = 0; k < 64; ++k) accS += s_s[rw][k] * Ws_s[k][e];
        float accA = ba_s[e];
        #pragma unroll
        for (int k = 0; k < 16; ++k) accA += a_s[rw][k] * Wa_s[k][e];
        float accR = br_s[e] + r_s[rw] * Wr_s[e];
        size_t base = (row0 + rw) * X_DIM;
        x[base + e]       = gelu_tanh(accS);
        x[base + 128 + e] = gelu_tanh(accA);
        x[base + 256 + e] = gelu_tanh(accR);
    }
}

// ---------------- Gates GEMM: C[m][n] = sum_k A[m][k]*B[k][n] + bias[n]
__global__ __launch_bounds__(256) void gates_gemm(
    const float* __restrict__ A, const float* __restrict__ B,
    const float* __restrict__ bias, float* __restrict__ C)
{
    __shared__ float As[32][132];
    __shared__ float Bs[32][132];
    const int K = X_DIM;
    int tid = threadIdx.x;
    size_t m0 = (size_t)blockIdx.x * 128;
    int n0 = blockIdx.y * 128;
    int tx = tid & 15, ty = tid >> 4;
    float acc[8][8] = {};
    for (int k0 = 0; k0 < K; k0 += 32) {
        #pragma unroll
        for (int p = 0; p < 4; ++p) {
            int row = (tid >> 3) + p * 32;
            int k4 = (tid & 7) * 4;
            float4 v = *reinterpret_cast<const float4*>(&A[(m0 + row) * K + k0 + k4]);
            As[k4 + 0][row] = v.x; As[k4 + 1][row] = v.y;
            As[k4 + 2][row] = v.z; As[k4 + 3][row] = v.w;
        }
        {
            int k = tid >> 3;
            int cb = (tid & 7) * 16;
            #pragma unroll
            for (int q = 0; q < 4; ++q) {
                float4 v = *reinterpret_cast<const float4*>(&B[(size_t)(k0 + k) * G_DIM + n0 + cb + q * 4]);
                *reinterpret_cast<float4*>(&Bs[k][cb + q * 4]) = v;
            }
        }
        __syncthreads();
        #pragma unroll
        for (int k = 0; k < 32; ++k) {
            float4 a0 = *reinterpret_cast<const float4*>(&As[k][ty * 8]);
            float4 a1 = *reinterpret_cast<const float4*>(&As[k][ty * 8 + 4]);
            float4 b0 = *reinterpret_cast<const float4*>(&Bs[k][tx * 8]);
            float4 b1 = *reinterpret_cast<const float4*>(&Bs[k][tx * 8 + 4]);
            float av[8] = {a0.x, a0.y, a0.z, a0.w, a1.x, a1.y, a1.z, a1.w};
            float bv[8] = {b0.x, b0.y, b0.z, b0.w, b1.x, b1.y, b1.z, b1.w};
            #pragma unroll
            for (int i = 0; i < 8; ++i)
                #pragma unroll
                for (int j = 0; j < 8; ++j)
                    acc[i][j] += av[i] * bv[j];
        }
        __syncthreads();
    }
    #pragma unroll
    for (int i = 0; i < 8; ++i) {
        size_t crow = (m0 + ty * 8 + i) * G_DIM + n0 + tx * 8;
        float4 o0, o1;
        o0.x = acc[i][0] + bias[n0 + tx * 8 + 0];
        o0.y = acc[i][1] + bias[n0 + tx * 8 + 1];
        o0.z = acc[i][2] + bias[n0 + tx * 8 + 2];
        o0.w = acc[i][3] + bias[n0 + tx * 8 + 3];
        o1.x = acc[i][4] + bias[n0 + tx * 8 + 4];
        o1.y = acc[i][5] + bias[n0 + tx * 8 + 5];
        o1.z = acc[i][6] + bias[n0 + tx * 8 + 6];
        o1.w = acc[i][7] + bias[n0 + tx * 8 + 7];
        *reinterpret_cast<float4*>(&C[crow]) = o0;
        *reinterpret_cast<float4*>(&C[crow + 4]) = o1;
    }
}

// ---------------- GRU step part 1: zr = sigmoid(gx_zr + h @ Wzr)
// grid (32, 8) = 256 blocks, 256 thr. Tile 32 rows x 32 cols of the 256x1024
// zr output. Micro 1m x 4n per thread. K=512 staged in 128-chunks with
// register-prefetch double buffering.
__global__ __launch_bounds__(256) void gru_zr(
    const float* __restrict__ gxb,   // B x 1536
    const float* __restrict__ hprev, // B x 512 or nullptr
    const float* __restrict__ w_h,   // 512 x 1536
    float* __restrict__ zbuf,        // B x 512
    float* __restrict__ rhbuf)       // B x 512
{
    __shared__ float h_s[32][132];   // [m][k] row stride 132 -> conflict-free
    __shared__ float w_s[128][36];   // [k][n] row stride 36 -> conflict-free
    const int tid = threadIdx.x;
    const int n0 = blockIdx.x * 32;  // 0..1023 (zr col space)
    const int m0 = blockIdx.y * 32;
    const int tx = tid & 7;          // 8 col-quads
    const int ty = tid >> 3;         // 32 rows
    float acc[4] = {0.f, 0.f, 0.f, 0.f};

    if (hprev) {
        float4 ph[4], pw[4];
        // prefetch chunk 0
        #pragma unroll
        for (int p = 0; p < 4; ++p) {
            int i = tid + p * 256;
            ph[p] = *reinterpret_cast<const float4*>(&hprev[(size_t)(m0 + (i >> 5)) * H_DIM + (i & 31) * 4]);
            pw[p] = *reinterpret_cast<const float4*>(&w_h[(size_t)(i >> 3) * G_DIM + n0 + (i & 7) * 4]);
        }
        for (int k0 = 0; k0 < H_DIM; k0 += 128) {
            #pragma unroll
            for (int p = 0; p < 4; ++p) {
                int i = tid + p * 256;
                *reinterpret_cast<float4*>(&h_s[i >> 5][(i & 31) * 4]) = ph[p];
                *reinterpret_cast<float4*>(&w_s[i >> 3][(i & 7) * 4]) = pw[p];
            }
            __syncthreads();
            if (k0 + 128 < H_DIM) {
                int kn = k0 + 128;
                #pragma unroll
                for (int p = 0; p < 4; ++p) {
                    int i = tid + p * 256;
                    ph[p] = *reinterpret_cast<const float4*>(&hprev[(size_t)(m0 + (i >> 5)) * H_DIM + kn + (i & 31) * 4]);
                    pw[p] = *reinterpret_cast<const float4*>(&w_h[(size_t)(kn + (i >> 3)) * G_DIM + n0 + (i & 7) * 4]);
                }
            }
            #pragma unroll
            for (int k = 0; k < 128; k += 4) {
                float4 a4 = *reinterpret_cast<const float4*>(&h_s[ty][k]);
                float4 b0 = *reinterpret_cast<const float4*>(&w_s[k + 0][tx * 4]);
                float4 b1 = *reinterpret_cast<const float4*>(&w_s[k + 1][tx * 4]);
                float4 b2 = *reinterpret_cast<const float4*>(&w_s[k + 2][tx * 4]);
                float4 b3 = *reinterpret_cast<const float4*>(&w_s[k + 3][tx * 4]);
                acc[0] = fmaf(a4.x, b0.x, acc[0]); acc[1] = fmaf(a4.x, b0.y, acc[1]);
                acc[2] = fmaf(a4.x, b0.z, acc[2]); acc[3] = fmaf(a4.x, b0.w, acc[3]);
                acc[0] = fmaf(a4.y, b1.x, acc[0]); acc[1] = fmaf(a4.y, b1.y, acc[1]);
                acc[2] = fmaf(a4.y, b1.z, acc[2]); acc[3] = fmaf(a4.y, b1.w, acc[3]);
                acc[0] = fmaf(a4.z, b2.x, acc[0]); acc[1] = fmaf(a4.z, b2.y, acc[1]);
                acc[2] = fmaf(a4.z, b2.z, acc[2]); acc[3] = fmaf(a4.z, b2.w, acc[3]);
                acc[0] = fmaf(a4.w, b3.x, acc[0]); acc[1] = fmaf(a4.w, b3.y, acc[1]);
                acc[2] = fmaf(a4.w, b3.z, acc[2]); acc[3] = fmaf(a4.w, b3.w, acc[3]);
            }
            __syncthreads();
        }
    }
    // epilogue
    int row = m0 + ty;
    int col = n0 + tx * 4;
    float4 g = *reinterpret_cast<const float4*>(&gxb[(size_t)row * G_DIM + col]);
    float v0 = sigmoidf(g.x + acc[0]);
    float v1 = sigmoidf(g.y + acc[1]);
    float v2 = sigmoidf(g.z + acc[2]);
    float v3 = sigmoidf(g.w + acc[3]);
    if (n0 < H_DIM) {
        float4 o = {v0, v1, v2, v3};
        *reinterpret_cast<float4*>(&zbuf[(size_t)row * H_DIM + col]) = o;
    } else {
        int c = col - H_DIM;
        float4 hp4 = {0.f, 0.f, 0.f, 0.f};
        if (hprev) hp4 = *reinterpret_cast<const float4*>(&hprev[(size_t)row * H_DIM + c]);
        float4 o = {v0 * hp4.x, v1 * hp4.y, v2 * hp4.z, v3 * hp4.w};
        *reinterpret_cast<float4*>(&rhbuf[(size_t)row * H_DIM + c]) = o;
    }
}

// ---------------- GRU step part 2: a = tanh(gx_a + rh @ Wa); h = hp + z*(a-hp)
// grid (16, 8) = 128 blocks, same tile structure as gru_zr.
__global__ __launch_bounds__(256) void gru_a(
    const float* __restrict__ gxb,   // B x 1536
    const float* __restrict__ hprev, // B x 512 or nullptr (rhbuf invalid at t=0)
    const float* __restrict__ rhbuf, // B x 512
    const float* __restrict__ zbuf,  // B x 512
    const float* __restrict__ w_h,   // 512 x 1536
    float* __restrict__ hout)        // B x 512
{
    __shared__ float h_s[32][132];
    __shared__ float w_s[128][36];
    const int tid = threadIdx.x;
    const int n0 = blockIdx.x * 32;  // 0..511 (a col space)
    const int m0 = blockIdx.y * 32;
    const int tx = tid & 7;
    const int ty = tid >> 3;
    float acc[4] = {0.f, 0.f, 0.f, 0.f};

    if (hprev) {
        float4 ph[4], pw[4];
        #pragma unroll
        for (int p = 0; p < 4; ++p) {
            int i = tid + p * 256;
            ph[p] = *reinterpret_cast<const float4*>(&rhbuf[(size_t)(m0 + (i >> 5)) * H_DIM + (i & 31) * 4]);
            pw[p] = *reinterpret_cast<const float4*>(&w_h[(size_t)(i >> 3) * G_DIM + 2 * H_DIM + n0 + (i & 7) * 4]);
        }
        for (int k0 = 0; k0 < H_DIM; k0 += 128) {
            #pragma unroll
            for (int p = 0; p < 4; ++p) {
                int i = tid + p * 256;
                *reinterpret_cast<float4*>(&h_s[i >> 5][(i & 31) * 4]) = ph[p];
                *reinterpret_cast<float4*>(&w_s[i >> 3][(i & 7) * 4]) = pw[p];
            }
            __syncthreads();
            if (k0 + 128 < H_DIM) {
                int kn = k0 + 128;
                #pragma unroll
                for (int p = 0; p < 4; ++p) {
                    int i = tid + p * 256;
                    ph[p] = *reinterpret_cast<const float4*>(&rhbuf[(size_t)(m0 + (i >> 5)) * H_DIM + kn + (i & 31) * 4]);
                    pw[p] = *reinterpret_cast<const float4*>(&w_h[(size_t)(kn + (i >> 3)) * G_DIM + 2 * H_DIM + n0 + (i & 7) * 4]);
                }
            }
            #pragma unroll
            for (int k = 0; k < 128; k += 4) {
                float4 a4 = *reinterpret_cast<const float4*>(&h_s[ty][k]);
                float4 b0 = *reinterpret_cast<const float4*>(&w_s[k + 0][tx * 4]);
                float4 b1 = *reinterpret_cast<const float4*>(&w_s[k + 1][tx * 4]);
                float4 b2 = *reinterpret_cast<const float4*>(&w_s[k + 2][tx * 4]);
                float4 b3 = *reinterpret_cast<const float4*>(&w_s[k + 3][tx * 4]);
                acc[0] = fmaf(a4.x, b0.x, acc[0]); acc[1] = fmaf(a4.x, b0.y, acc[1]);
                acc[2] = fmaf(a4.x, b0.z, acc[2]); acc[3] = fmaf(a4.x, b0.w, acc[3]);
                acc[0] = fmaf(a4.y, b1.x, acc[0]); acc[1] = fmaf(a4.y, b1.y, acc[1]);
                acc[2] = fmaf(a4.y, b1.z, acc[2]); acc[3] = fmaf(a4.y, b1.w, acc[3]);
                acc[0] = fmaf(a4.z, b2.x, acc[0]); acc[1] = fmaf(a4.z, b2.y, acc[1]);
                acc[2] = fmaf(a4.z, b2.z, acc[2]); acc[3] = fmaf(a4.z, b2.w, acc[3]);
                acc[0] = fmaf(a4.w, b3.x, acc[0]); acc[1] = fmaf(a4.w, b3.y, acc[1]);
                acc[2] = fmaf(a4.w, b3.z, acc[2]); acc[3] = fmaf(a4.w, b3.w, acc[3]);
            }
            __syncthreads();
        }
    }
    int row = m0 + ty;
    int col = n0 + tx * 4;
    float4 g = *reinterpret_cast<const float4*>(&gxb[(size_t)row * G_DIM + 2 * H_DIM + col]);
    float a0 = tanhf(g.x + acc[0]);
    float a1 = tanhf(g.y + acc[1]);
    float a2 = tanhf(g.z + acc[2]);
    float a3 = tanhf(g.w + acc[3]);
    float4 hp4 = {0.f, 0.f, 0.f, 0.f};
    if (hprev) hp4 = *reinterpret_cast<const float4*>(&hprev[(size_t)row * H_DIM + col]);
    float4 z4 = *reinterpret_cast<const float4*>(&zbuf[(size_t)row * H_DIM + col]);
    float4 o;
    o.x = hp4.x + z4.x * (a0 - hp4.x);
    o.y = hp4.y + z4.y * (a1 - hp4.y);
    o.z = hp4.z + z4.z * (a2 - hp4.z);
    o.w = hp4.w + z4.w * (a3 - hp4.w);
    *reinterpret_cast<float4*>(&hout[(size_t)row * H_DIM + col]) = o;
}

extern "C" void kernel_launch(void* const* d_in, const int* in_sizes, int n_in,
                              void* d_out, int out_size, void* d_ws, size_t ws_size,
                              hipStream_t stream) {
    const float* states  = (const float*)d_in[0];
    const float* actions = (const float*)d_in[1];
    const float* rewards = (const float*)d_in[2];
    const float* Ws   = (const float*)d_in[3];
    const float* bs   = (const float*)d_in[4];
    const float* Wa   = (const float*)d_in[5];
    const float* ba   = (const float*)d_in[6];
    const float* Wr   = (const float*)d_in[7];
    const float* br   = (const float*)d_in[8];
    const float* w_i  = (const float*)d_in[9];
    const float* w_h  = (const float*)d_in[10];
    const float* bgru = (const float*)d_in[11];
    float* out = (float*)d_out;

    // ws layout: [zbuf: B*512][rhbuf: B*512][gx: chunk*B*1536][xbuf: chunk*B*384]
    size_t fixed = (size_t)2 * B_DIM * H_DIM * sizeof(float);
    size_t per_step = (size_t)B_DIM * (G_DIM + X_DIM) * sizeof(float);
    int chunk = (int)((ws_size > fixed ? ws_size - fixed : 0) / per_step);
    if (chunk > T_DIM) chunk = T_DIM;
    if (chunk < 1) chunk = 1;
    float* zbuf  = (float*)d_ws;
    float* rhbuf = zbuf + (size_t)B_DIM * H_DIM;
    float* gx    = rhbuf + (size_t)B_DIM * H_DIM;
    float* xbuf  = gx + (size_t)chunk * B_DIM * G_DIM;

    for (int t0 = 0; t0 < T_DIM; t0 += chunk) {
        int nt = (T_DIM - t0 < chunk) ? (T_DIM - t0) : chunk;
        int rows = nt * B_DIM;
        embed_kernel<<<rows / 64, 256, 0, stream>>>(
            states + (size_t)t0 * B_DIM * S_DIMS,
            actions + (size_t)t0 * B_DIM * A_DIMS,
            rewards + (size_t)t0 * B_DIM,
            Ws, bs, Wa, ba, Wr, br, xbuf);
        dim3 ggrid(rows / 128, G_DIM / 128);
        gates_gemm<<<ggrid, 256, 0, stream>>>(xbuf, w_i, bgru, gx);
        for (int s = 0; s < nt; ++s) {
            int t = t0 + s;
            const float* hprev = (t == 0) ? nullptr : out + (size_t)(t - 1) * B_DIM * H_DIM;
            const float* gxb = gx + (size_t)s * B_DIM * G_DIM;
            dim3 zgrid(2 * H_DIM / 32, B_DIM / 32);   // (32, 8) = 256 blocks
            gru_zr<<<zgrid, 256, 0, stream>>>(gxb, hprev, w_h, zbuf, rhbuf);
            dim3 agrid(H_DIM / 32, B_DIM / 32);       // (16, 8) = 128 blocks
            gru_a<<<agrid, 256, 0, stream>>>(gxb, hprev, rhbuf, zbuf, w_h,
                                             out + (size_t)t * B_DIM * H_DIM);
        }
    }
}